// Round 3
// baseline (18477.953 us; speedup 1.0000x reference)
//
#include <hip/hip_runtime.h>

// HighwayLayerDiscrete: 256-step recurrent highway net, batch 64, units 1024.
// Phase P = t*4+p: p0: h=lrelu(y@w_y + xproj[t]); p1/p2: h=lrelu(h@w_h[l]+b_h[l]);
// p3: y += h@w_out + b_out; out[:,t,:]=y.
//
// R3: split-K producers accumulate DIRECTLY into the next activation buffer
// via device-scope fp32 atomic adds (unsafeAtomicAdd -> global_atomic_add_f32,
// executes at the coherence point). No partial buffers, no reduce step, ONE
// flag round per phase. Slots[4] (one per phase type); slot q holds the
// pre-activation accumulator; consumers apply lrelu on load (p3 slot = y
// itself, never reset -> highway accumulation is the atomic accumulator).
// Bias init for phase P+1 is written by phase-P WGs (stores for p0/p1/p2,
// b_out ADD for p3); safety: flag[P][g] full => all flags[P-1] full => all
// P-2 reads retired (4-slot reuse distance = safe).
// R2 lessons kept: no fences ever (plain loads for W stay L1/L2-hot), sc1
// (agent-scope relaxed atomic) loads for cross-WG data, stride-68 LDS (0
// conflicts). R2 lessons fixed: poll only from tid==0 with s_sleep backoff
// (R2's 1024-wave spin storm inflated every LLC round trip); no write-through
// scalar-store partials (17GB EA write traffic -> atomic adds).

constexpr int B = 64, T = 256, U = 1024, E = 512;
constexpr int BU = B * U;  // 65536

#define LRELU(v) ((v) > 0.f ? (v) : 0.2f * (v))

__device__ __forceinline__ unsigned long long llc_load64(const float* p) {
  return __hip_atomic_load((const unsigned long long*)p, __ATOMIC_RELAXED,
                           __HIP_MEMORY_SCOPE_AGENT);
}
__device__ __forceinline__ void llc_store(float* p, float v) {
  __hip_atomic_store(p, v, __ATOMIC_RELAXED, __HIP_MEMORY_SCOPE_AGENT);
}
__device__ __forceinline__ unsigned llc_flag(const unsigned* p) {
  return __hip_atomic_load(p, __ATOMIC_RELAXED, __HIP_MEMORY_SCOPE_AGENT);
}

// ---------------- init: zero flags, slot3 = broadcast(h0) (= y0) ----------
__global__ void k_init(float* __restrict__ slot3, const float* __restrict__ h0,
                       unsigned* __restrict__ flags) {
  int tid = blockIdx.x * 256 + threadIdx.x;
  if (tid < 1024) flags[tid] = 0u;
  if (tid < BU) slot3[tid] = h0[tid & (U - 1)];
}

// ------- xproj[t*64+n][u] = emb[x[n][t]] @ w_x + b_in; t=0 also -> slot0 ----
__global__ __launch_bounds__(256) void k_xproj(
    const int* __restrict__ x, const float* __restrict__ emb,
    const float* __restrict__ w_x, const float* __restrict__ b_in,
    float* __restrict__ xp, float* __restrict__ slot0) {
  __shared__ float a_s[64][36];
  __shared__ float w_s[32][64];
  __shared__ int idxs[64];
  const int tid = threadIdx.x;
  const int m0 = blockIdx.x * 64;
  const int c0 = blockIdx.y * 64;
  if (tid < 64) {
    int m = m0 + tid;
    idxs[tid] = x[(m & 63) * T + (m >> 6)];  // x[n][t], row m = t*64+n
  }
  __syncthreads();
  const int rq = tid >> 4, cq = tid & 15;
  float acc[4][4] = {};
  for (int k0 = 0; k0 < E; k0 += 32) {
#pragma unroll
    for (int rep = 0; rep < 8; ++rep) {  // A: 64 rows x 32 k
      int e = rep * 256 + tid;
      int r = e >> 5, k = e & 31;
      a_s[r][k] = emb[(size_t)idxs[r] * E + k0 + k];
    }
#pragma unroll
    for (int rep = 0; rep < 2; ++rep) {  // W: 32 k x 16 float4
      int e = rep * 256 + tid;
      int kr = e >> 4, q = e & 15;
      *(float4*)&w_s[kr][4 * q] =
          *(const float4*)(w_x + (size_t)(k0 + kr) * U + c0 + 4 * q);
    }
    __syncthreads();
#pragma unroll
    for (int kc = 0; kc < 32; kc += 4) {
      float4 a4[4], w4[4];
#pragma unroll
      for (int i = 0; i < 4; ++i) a4[i] = *(const float4*)&a_s[4 * rq + i][kc];
#pragma unroll
      for (int kk = 0; kk < 4; ++kk)
        w4[kk] = *(const float4*)&w_s[kc + kk][4 * cq];
#pragma unroll
      for (int i = 0; i < 4; ++i) {
        const float av[4] = {a4[i].x, a4[i].y, a4[i].z, a4[i].w};
#pragma unroll
        for (int kk = 0; kk < 4; ++kk) {
          acc[i][0] += av[kk] * w4[kk].x;
          acc[i][1] += av[kk] * w4[kk].y;
          acc[i][2] += av[kk] * w4[kk].z;
          acc[i][3] += av[kk] * w4[kk].w;
        }
      }
    }
    __syncthreads();
  }
  const float4 bb = *(const float4*)(b_in + c0 + 4 * cq);
  const float bv[4] = {bb.x, bb.y, bb.z, bb.w};
#pragma unroll
  for (int i = 0; i < 4; ++i) {
    float4 o;
    o.x = acc[i][0] + bv[0];
    o.y = acc[i][1] + bv[1];
    o.z = acc[i][2] + bv[2];
    o.w = acc[i][3] + bv[3];
    *(float4*)(xp + (size_t)(m0 + 4 * rq + i) * U + c0 + 4 * cq) = o;
    if (m0 == 0)  // t = 0 -> pre-init slot0 (phase-0 accumulator)
      *(float4*)(slot0 + (size_t)(4 * rq + i) * U + c0 + 4 * cq) = o;
  }
}

// ---------------- sequential pipeline ----------------
// 256 WGs = 16 col-groups(c) x 16 K-groups(s). Per phase P: WG(c,s)
//  1. polls flag[s] (A cols ready) and flag[c] (own-output init ready)
//  2. stages A = f(slot[(P-1)&3][0..63][64s..64s+64]) (f=lrelu unless prev
//     phase was p3); p0/c0 WGs also write out[:,t-1,:] slice from staged y
//  3. writes bias-init for phase P+1 into slot[(P+1)&3] (rows 4s..4s+4,
//     cols 64c..64c+64)
//  4. computes 64x64 x K=64 FMA tile, atomic-adds into slot[P&3]
//  5. drains (vmcnt 0 + barrier), posts flag[c]
__global__ __launch_bounds__(256, 1) void k_seq(
    const float* __restrict__ xproj, const float* __restrict__ w_y,
    const float* __restrict__ w_h, const float* __restrict__ b_h,
    const float* __restrict__ w_out, const float* __restrict__ b_out,
    float* __restrict__ out, float* __restrict__ slots,
    unsigned* __restrict__ flags) {
  __shared__ float a_s[64][68];  // stride 68 -> 0 bank conflicts (R2 measured)
  __shared__ float w_s[64][64];
  const int tid = threadIdx.x;
  const int c = blockIdx.x & 15;  // col-group
  const int s = blockIdx.x >> 4;  // K-group
  const int rq = tid >> 4, cq = tid & 15;

  for (int P = 0; P < 4 * T; ++P) {
    const int t = P >> 2, p = P & 3;
    const float* Wsrc = (p == 0)   ? w_y
                        : (p == 3) ? w_out
                                   : w_h + (size_t)(p - 1) * U * U;
    const float* Asl = slots + (size_t)((P + 3) & 3) * BU;  // prev phase slot
    const bool act = ((P + 3) & 3) != 3;  // prev phase p3 -> A=y, no lrelu
    // ---- 1. poll both flags (tid==0 only, backoff) ----
    if (P > 0) {
      if (tid == 0) {
        const unsigned tg = 16u * (unsigned)P;
        while (llc_flag(&flags[s * 32]) < tg) __builtin_amdgcn_s_sleep(1);
        if (c != s)
          while (llc_flag(&flags[c * 32]) < tg) __builtin_amdgcn_s_sleep(1);
      }
      __syncthreads();
      asm volatile("" ::: "memory");
    }
    // ---- 2. stage A (8B sc1 loads), apply activation; p0/c0 -> out ----
    {
      const float* Ab = Asl + s * 64;
#pragma unroll
      for (int rep = 0; rep < 8; ++rep) {  // 64 rows x 32 ull
        int e = rep * 256 + tid;
        int r = e >> 5, kq = e & 31;
        unsigned long long v = llc_load64(Ab + (size_t)r * U + 2 * kq);
        float f0 = __uint_as_float((unsigned)v);
        float f1 = __uint_as_float((unsigned)(v >> 32));
        if (act) {
          f0 = LRELU(f0);
          f1 = LRELU(f1);
        }
        a_s[r][2 * kq] = f0;
        a_s[r][2 * kq + 1] = f1;
        if (p == 0 && c == 0 && t > 0) {  // staged y == out[:, t-1, cols]
          float2 o = {f0, f1};
          *(float2*)(out + ((size_t)r * T + (t - 1)) * U + s * 64 + 2 * kq) = o;
        }
      }
    }
    // ---- 3. init for phase P+1 (overlaps with W-stage/compute latency) ----
    if (P < 4 * T - 1) {
      const int pn = (P + 1) & 3, tn = (P + 1) >> 2;
      const int r0 = 4 * s + (tid >> 6);
      const int u = c * 64 + (tid & 63);
      float* dst = slots + (size_t)pn * BU + (size_t)r0 * U + u;
      if (pn == 0)
        llc_store(dst, xproj[((size_t)tn * 64 + r0) * U + u]);
      else if (pn < 3)
        llc_store(dst, b_h[(pn - 1) * U + u]);
      else
        unsafeAtomicAdd(dst, b_out[u]);  // slot3 = y accumulator, add only
    }
    // ---- stage W (plain cached loads, L2-hot) ----
#pragma unroll
    for (int rep = 0; rep < 4; ++rep) {  // 64 k x 16 float4
      int e = rep * 256 + tid;
      int kr = e >> 4, q = e & 15;
      *(float4*)&w_s[kr][4 * q] =
          *(const float4*)(Wsrc + (size_t)(s * 64 + kr) * U + c * 64 + 4 * q);
    }
    __syncthreads();
    // ---- 4. compute 64x64 tile over K-slice 64 ----
    float acc[4][4] = {};
#pragma unroll
    for (int kc = 0; kc < 64; kc += 4) {
      float4 a4[4], w4[4];
#pragma unroll
      for (int i = 0; i < 4; ++i) a4[i] = *(const float4*)&a_s[4 * rq + i][kc];
#pragma unroll
      for (int kk = 0; kk < 4; ++kk)
        w4[kk] = *(const float4*)&w_s[kc + kk][4 * cq];
#pragma unroll
      for (int i = 0; i < 4; ++i) {
        const float av[4] = {a4[i].x, a4[i].y, a4[i].z, a4[i].w};
#pragma unroll
        for (int kk = 0; kk < 4; ++kk) {
          acc[i][0] += av[kk] * w4[kk].x;
          acc[i][1] += av[kk] * w4[kk].y;
          acc[i][2] += av[kk] * w4[kk].z;
          acc[i][3] += av[kk] * w4[kk].w;
        }
      }
    }
    // ---- atomic-accumulate into slot[P&3] ----
    {
      float* base = slots + (size_t)(P & 3) * BU + c * 64 + 4 * cq;
#pragma unroll
      for (int i = 0; i < 4; ++i)
#pragma unroll
        for (int j = 0; j < 4; ++j)
          unsafeAtomicAdd(base + (size_t)(4 * rq + i) * U + j, acc[i][j]);
    }
    // ---- 5. drain + post ----
    asm volatile("" ::: "memory");
    __builtin_amdgcn_s_waitcnt(0);
    __syncthreads();
    if (tid == 0)
      __hip_atomic_fetch_add(&flags[c * 32], 1u, __ATOMIC_RELAXED,
                             __HIP_MEMORY_SCOPE_AGENT);
  }
  // ---- final: out[:, 255, :] = y_255 (slot3) ----
  if (c == 0) {
    if (tid == 0) {
      const unsigned tg = 16u * (unsigned)(4 * T);
      while (llc_flag(&flags[s * 32]) < tg) __builtin_amdgcn_s_sleep(1);
    }
    __syncthreads();
    asm volatile("" ::: "memory");
    const float* y = slots + 3 * (size_t)BU + s * 64;
#pragma unroll
    for (int rep = 0; rep < 8; ++rep) {
      int e = rep * 256 + tid;
      int r = e >> 5, kq = e & 31;
      unsigned long long v = llc_load64(y + (size_t)r * U + 2 * kq);
      float2 o = {__uint_as_float((unsigned)v),
                  __uint_as_float((unsigned)(v >> 32))};
      *(float2*)(out + ((size_t)r * T + (T - 1)) * U + s * 64 + 2 * kq) = o;
    }
  }
}

extern "C" void kernel_launch(void* const* d_in, const int* in_sizes, int n_in,
                              void* d_out, int out_size, void* d_ws,
                              size_t ws_size, hipStream_t stream) {
  const int* x = (const int*)d_in[0];
  const float* emb = (const float*)d_in[1];
  const float* w_y = (const float*)d_in[2];
  const float* w_x = (const float*)d_in[3];
  const float* b_in = (const float*)d_in[4];
  const float* w_h = (const float*)d_in[5];
  const float* b_h = (const float*)d_in[6];
  const float* w_out = (const float*)d_in[7];
  const float* b_out = (const float*)d_in[8];
  const float* h0 = (const float*)d_in[9];
  float* out = (float*)d_out;

  // workspace (floats): xproj | slots[4] | flags
  float* ws = (float*)d_ws;
  float* xp = ws;                        // T*B*U = 16777216
  float* slots = xp + (size_t)T * B * U; // 4*BU
  unsigned* flags = (unsigned*)(slots + 4 * (size_t)BU);  // 1024 uints

  k_init<<<256, 256, 0, stream>>>(slots + 3 * (size_t)BU, h0, flags);
  dim3 g1(256, 16);
  k_xproj<<<g1, 256, 0, stream>>>(x, emb, w_x, b_in, xp, slots);

  void* args[] = {&xp, &w_y, &w_h, &b_h, &w_out, &b_out, &out, &slots, &flags};
  hipLaunchCooperativeKernel((void*)k_seq, dim3(256), dim3(256), args, 0u,
                             stream);
}

// Round 6
// 6983.054 us; speedup vs baseline: 2.6461x; 2.6461x over previous
//
#include <hip/hip_runtime.h>

// HighwayLayerDiscrete: 256-step recurrent highway net, batch 64, units 1024.
// Phase P = t*4+p: p0: h=lrelu(y@w_y + xproj[t]); p1/p2: h=lrelu(h@w_h[l]+b_h[l]);
// p3: y += h@w_out + b_out; out[:,t,:]=y.
//
// R6 = R5 with ONE fix: the LDS skew. R5's `k + 4*((k>>5)&7)` is NON-INJECTIVE
// (offset wraps every 8th 32-chunk -> k in [228,256) collided with [256,284)
// -> corrupted A every phase -> ref-magnitude absmax). Now pitch 1152, skew
// 4*(k>>5): chunk c -> [36c, 36c+32), disjoint (gap 4). Banks: compute reads
// at 36s+4q -> 4 s-groups on distinct bank quads, 2-way ri alias = free.
//
// Structure (validated pieces): 256 cooperative blocks (R1-R3 proven launch
// shape; R4's 512 blocks silently failed to launch) x 512 threads. WG(rg,cg):
// rows [8rg,8rg+8) x cols [32cg,32cg+32), FULL K=1024 in-WG (no cross-WG
// split-K: R2/R3 showed partial exchange = ~1-2M small LLC transactions =
// the wall). In-WG K-split 32-way + LDS reduce (stride 33). W read straight
// from per-XCD L2 into registers (plain loads; blockIdx->XCD = cg&7 keeps
// W column-slices resident). Activation applied ONCE at store.
// Coherence (R2/R3-proven): cross-WG data via relaxed agent-scope atomics
// (sc1 at LLC); release = s_waitcnt 0 + barrier + relaxed flag add; acquire =
// tid0 poll + barrier + asm clobber. NO fences (R1: buffer_wbl2/inv = 66 ms).
// ybuf (y residual) is per-WG-private plain memory; out written only at p3.

constexpr int B = 64, T = 256, U = 1024, E = 512;
constexpr int BU = B * U;  // 65536
constexpr int APITCH = 1152;  // A-row pitch in LDS (1024 + 128 skew)

#define LRELU(v) ((v) > 0.f ? (v) : 0.2f * (v))

using f4 = float __attribute__((ext_vector_type(4)));

__device__ __forceinline__ unsigned long long llc_load64(const float* p) {
  return __hip_atomic_load((const unsigned long long*)p, __ATOMIC_RELAXED,
                           __HIP_MEMORY_SCOPE_AGENT);
}
__device__ __forceinline__ void llc_store(float* p, float v) {
  __hip_atomic_store(p, v, __ATOMIC_RELAXED, __HIP_MEMORY_SCOPE_AGENT);
}
__device__ __forceinline__ unsigned llc_flag(const unsigned* p) {
  return __hip_atomic_load(p, __ATOMIC_RELAXED, __HIP_MEMORY_SCOPE_AGENT);
}

// ---------------- init: zero flags, y0 into slot1 and ybuf ----------------
__global__ void k_init(float* __restrict__ slot1, float* __restrict__ ybuf,
                       const float* __restrict__ h0,
                       unsigned* __restrict__ flags) {
  int tid = blockIdx.x * 256 + threadIdx.x;
  if (tid < 512) flags[tid] = 0u;
  if (tid < BU) {
    float v = h0[tid & (U - 1)];
    slot1[tid] = v;
    ybuf[tid] = v;
  }
}

// ------- xproj[t*64+n][u] = emb[x[n][t]] @ w_x + b_in (R2/R3-proven) -------
__global__ __launch_bounds__(256) void k_xproj(
    const int* __restrict__ x, const float* __restrict__ emb,
    const float* __restrict__ w_x, const float* __restrict__ b_in,
    float* __restrict__ xp) {
  __shared__ float a_s[64][36];
  __shared__ float w_s[32][64];
  __shared__ int idxs[64];
  const int tid = threadIdx.x;
  const int m0 = blockIdx.x * 64;
  const int c0 = blockIdx.y * 64;
  if (tid < 64) {
    int m = m0 + tid;
    idxs[tid] = x[(m & 63) * T + (m >> 6)];  // x[n][t], row m = t*64+n
  }
  __syncthreads();
  const int rq = tid >> 4, cq = tid & 15;
  float acc[4][4] = {};
  for (int k0 = 0; k0 < E; k0 += 32) {
#pragma unroll
    for (int rep = 0; rep < 8; ++rep) {
      int e = rep * 256 + tid;
      int r = e >> 5, k = e & 31;
      a_s[r][k] = emb[(size_t)idxs[r] * E + k0 + k];
    }
#pragma unroll
    for (int rep = 0; rep < 2; ++rep) {
      int e = rep * 256 + tid;
      int kr = e >> 4, q = e & 15;
      *(float4*)&w_s[kr][4 * q] =
          *(const float4*)(w_x + (size_t)(k0 + kr) * U + c0 + 4 * q);
    }
    __syncthreads();
#pragma unroll
    for (int kc = 0; kc < 32; kc += 4) {
      float4 a4[4], w4[4];
#pragma unroll
      for (int i = 0; i < 4; ++i) a4[i] = *(const float4*)&a_s[4 * rq + i][kc];
#pragma unroll
      for (int kk = 0; kk < 4; ++kk)
        w4[kk] = *(const float4*)&w_s[kc + kk][4 * cq];
#pragma unroll
      for (int i = 0; i < 4; ++i) {
        const float av[4] = {a4[i].x, a4[i].y, a4[i].z, a4[i].w};
#pragma unroll
        for (int kk = 0; kk < 4; ++kk) {
          acc[i][0] += av[kk] * w4[kk].x;
          acc[i][1] += av[kk] * w4[kk].y;
          acc[i][2] += av[kk] * w4[kk].z;
          acc[i][3] += av[kk] * w4[kk].w;
        }
      }
    }
    __syncthreads();
  }
  const float4 bb = *(const float4*)(b_in + c0 + 4 * cq);
  const float bv[4] = {bb.x, bb.y, bb.z, bb.w};
#pragma unroll
  for (int i = 0; i < 4; ++i) {
    float4 o;
    o.x = acc[i][0] + bv[0];
    o.y = acc[i][1] + bv[1];
    o.z = acc[i][2] + bv[2];
    o.w = acc[i][3] + bv[3];
    *(float4*)(xp + (size_t)(m0 + 4 * rq + i) * U + c0 + 4 * cq) = o;
  }
}

// ---------------- sequential pipeline ----------------
// 256 WGs = 8 rg x 32 cg (XCD = blockIdx&7 = cg&7, L2-affine). Thread
// (s,ri,ci): s = K-slice [32s,32s+32) (32-way in-WG split), rows [4ri,4ri+4)
// of 8, cols [4ci,4ci+4) of 32. Partials -> red[out][s] stride 33 (2-way =
// free). a_s (8 x APITCH = 9216 floats) ALIASES red (256x33 = 8448) —
// barriers order last-A-read < red-write < red-read < next-phase A-write.
__global__ __launch_bounds__(512, 2) void k_seq(
    const float* __restrict__ xp, const float* __restrict__ w_y,
    const float* __restrict__ w_h, const float* __restrict__ b_h,
    const float* __restrict__ w_out, const float* __restrict__ b_out,
    float* __restrict__ out, float* __restrict__ slots,
    float* __restrict__ ybuf, unsigned* __restrict__ flags) {
  __shared__ float smem[8 * APITCH];  // 9216 floats = 36864 B
  float* const a_s = smem;  // [row][k + 4*(k>>5)], pitch APITCH (injective!)
  float* const red = smem;  // [out][s], stride 33 (alias — see barriers)
  const int tid = threadIdx.x;
  const int cg = blockIdx.x & 31, rg = blockIdx.x >> 5;
  const int l = tid & 63;
  const int ci = l & 7, ri = (l >> 3) & 1;
  const int s = (tid >> 6) * 4 + ((l >> 4) & 3);
  const int cb = 4 * ci, r0 = 4 * ri, k0 = 32 * s;

  for (int P = 0; P < 4 * T; ++P) {
    const int t = P >> 2, p = P & 3;
    const float* Wsrc = (p == 0)   ? w_y
                        : (p == 3) ? w_out
                                   : w_h + (size_t)(p - 1) * U * U;
    const float* Asrc =
        slots + (size_t)((P + 1) & 1) * BU + (size_t)(8 * rg) * U;
    float* slotw = slots + (size_t)(P & 1) * BU;
    // ---- 1. poll flag[rg]: all 32 producers of rows [8rg,8rg+8) done ----
    if (P > 0) {
      if (tid == 0) {
        const unsigned tg = 32u * (unsigned)P;
        while (llc_flag(&flags[rg * 32]) < tg) __builtin_amdgcn_s_sleep(1);
      }
      __syncthreads();
      asm volatile("" ::: "memory");
    }
    // ---- 2. stage A: 8 rows x 1024 (8B sc1 loads -> skewed LDS) ----
#pragma unroll
    for (int rep = 0; rep < 4; ++rep) {
      int idx4 = 512 * rep + tid;  // f4 index in [0,2048)
      int row = idx4 >> 8, kq = idx4 & 255, k = 4 * kq;
      const float* pa = Asrc + (size_t)row * U + k;
      unsigned long long v0 = llc_load64(pa);
      unsigned long long v1 = llc_load64(pa + 2);
      int ai = row * APITCH + k + 4 * (k >> 5);
      *(unsigned long long*)&a_s[ai] = v0;
      *(unsigned long long*)&a_s[ai + 2] = v1;
    }
    __syncthreads();
    // ---- 3. main: 4x4 tile over 32-k slice; W straight from L2 ----
    f4 acc[4];
#pragma unroll
    for (int i = 0; i < 4; ++i) acc[i] = (f4){0.f, 0.f, 0.f, 0.f};
    {
      const float* wp = Wsrc + (size_t)k0 * U + 32 * cg + cb;
      const int abase = r0 * APITCH;
#pragma unroll
      for (int q = 0; q < 8; ++q) {
        const int k = k0 + 4 * q;
        const int ai = abase + k + 4 * (k >> 5);
        f4 a0 = *(const f4*)&a_s[ai];
        f4 a1 = *(const f4*)&a_s[ai + APITCH];
        f4 a2 = *(const f4*)&a_s[ai + 2 * APITCH];
        f4 a3 = *(const f4*)&a_s[ai + 3 * APITCH];
        const float* wq = wp + (size_t)(4 * q) * U;
        f4 w0 = *(const f4*)(wq);
        f4 w1 = *(const f4*)(wq + U);
        f4 w2 = *(const f4*)(wq + 2 * U);
        f4 w3 = *(const f4*)(wq + 3 * U);
        acc[0] += a0.x * w0 + a0.y * w1 + a0.z * w2 + a0.w * w3;
        acc[1] += a1.x * w0 + a1.y * w1 + a1.z * w2 + a1.w * w3;
        acc[2] += a2.x * w0 + a2.y * w1 + a2.z * w2 + a2.w * w3;
        acc[3] += a3.x * w0 + a3.y * w1 + a3.z * w2 + a3.w * w3;
      }
    }
    __syncthreads();  // all a_s reads done -> safe to alias-write red
    // ---- 4. write partials red[out*33 + s] ----
#pragma unroll
    for (int i = 0; i < 4; ++i)
#pragma unroll
      for (int j = 0; j < 4; ++j)
        red[((r0 + i) * 32 + cb + j) * 33 + s] = acc[i][j];
    __syncthreads();
    // ---- 5. finalize: 256 threads, sum 32 partials, bias+act, store ----
    if (tid < 256) {
      float sum = 0.f;
#pragma unroll
      for (int z = 0; z < 32; ++z) sum += red[tid * 33 + z];
      const int row = 8 * rg + (tid >> 5);
      const int u = 32 * cg + (tid & 31);
      if (p == 0) {
        float v = sum + xp[((size_t)t * B + row) * U + u];
        llc_store(slotw + (size_t)row * U + u, LRELU(v));
      } else if (p < 3) {
        float v = sum + b_h[(p - 1) * U + u];
        llc_store(slotw + (size_t)row * U + u, LRELU(v));
      } else {
        const size_t yi = (size_t)row * U + u;
        float yn = ybuf[yi] + sum + b_out[u];  // WG-private: plain ok
        ybuf[yi] = yn;
        out[((size_t)row * T + t) * U + u] = yn;
        llc_store(slotw + yi, yn);  // y is next p0's A
      }
    }
    // ---- 6. drain + post ----
    asm volatile("" ::: "memory");
    __builtin_amdgcn_s_waitcnt(0);
    __syncthreads();
    if (tid == 0)
      __hip_atomic_fetch_add(&flags[rg * 32], 1u, __ATOMIC_RELAXED,
                             __HIP_MEMORY_SCOPE_AGENT);
  }
}

extern "C" void kernel_launch(void* const* d_in, const int* in_sizes, int n_in,
                              void* d_out, int out_size, void* d_ws,
                              size_t ws_size, hipStream_t stream) {
  const int* x = (const int*)d_in[0];
  const float* emb = (const float*)d_in[1];
  const float* w_y = (const float*)d_in[2];
  const float* w_x = (const float*)d_in[3];
  const float* b_in = (const float*)d_in[4];
  const float* w_h = (const float*)d_in[5];
  const float* b_h = (const float*)d_in[6];
  const float* w_out = (const float*)d_in[7];
  const float* b_out = (const float*)d_in[8];
  const float* h0 = (const float*)d_in[9];
  float* out = (float*)d_out;

  // workspace (floats): xproj | slots[2] | ybuf | flags
  float* ws = (float*)d_ws;
  float* xpb = ws;                         // T*B*U
  float* slots = xpb + (size_t)T * B * U;  // 2*BU
  float* ybuf = slots + 2 * (size_t)BU;    // BU
  unsigned* flags = (unsigned*)(ybuf + (size_t)BU);  // 512 uints

  k_init<<<256, 256, 0, stream>>>(slots + (size_t)BU, ybuf, h0, flags);
  dim3 g1(256, 16);
  k_xproj<<<g1, 256, 0, stream>>>(x, emb, w_x, b_in, xpb);

  void* args[] = {&xpb,   &w_y, &w_h,   &b_h,  &w_out,
                  &b_out, &out, &slots, &ybuf, &flags};
  hipLaunchCooperativeKernel((void*)k_seq, dim3(256), dim3(512), args, 0u,
                             stream);
}

// Round 7
// 6566.436 us; speedup vs baseline: 2.8140x; 1.0634x over previous
//
#include <hip/hip_runtime.h>

// HighwayLayerDiscrete: 256-step recurrent highway net, batch 64, units 1024.
// Phase P = t*4+p: p0: h=lrelu(y@w_y + xproj[t]); p1/p2: h=lrelu(h@w_h[l]+b_h[l]);
// p3: y += h@w_out + b_out; out[:,t,:]=y.
//
// R7 = R6 (correct, 6.98 ms) + three latency/LDS fixes:
//  1. W REGISTER PREFETCH one phase ahead (weights are static!): wreg[32] f4
//     (128 VGPRs) loaded in P's tail after the drain barrier -> L2 W latency
//     + BW overlaps flag post / poll / A-stage. Compute loop = LDS-A x reg-W.
//  2. A-staging writes as single b128 (R6's paired b64 writes hit 8 lanes per
//     bank-pair -> 3.36e8 SQ_LDS_BANK_CONFLICT; b128 8-per-quad = inherent min).
//  3. red transposed to [s][out] pitch 264 -> partial writes 4xb128 at
//     inherent-min bank spread; APITCH 1156 (==4 mod 8) -> compute reads hit
//     all 8 bank quads exactly once.
// Carried invariants: 256 coop blocks x 512 thr (R4: >256 blocks silently
// fails); no cross-WG split-K (R2/R3: partial exchange = ~1-2M LLC trans =
// wall); no fences ever (R1: buffer_wbl2/inv = 66 ms); cross-WG data via
// relaxed agent-scope atomics (sc1 at LLC); release = waitcnt0+barrier+flag;
// acquire = tid0 poll + barrier + asm clobber; LDS skew injective (R5 bug).

constexpr int B = 64, T = 256, U = 1024, E = 512;
constexpr int BU = B * U;     // 65536
constexpr int APITCH = 1156;  // A-row pitch (1024 + 36-skew; ==4 mod 8)

#define LRELU(v) ((v) > 0.f ? (v) : 0.2f * (v))

using f4 = float __attribute__((ext_vector_type(4)));

__device__ __forceinline__ unsigned long long llc_load64(const float* p) {
  return __hip_atomic_load((const unsigned long long*)p, __ATOMIC_RELAXED,
                           __HIP_MEMORY_SCOPE_AGENT);
}
__device__ __forceinline__ void llc_store(float* p, float v) {
  __hip_atomic_store(p, v, __ATOMIC_RELAXED, __HIP_MEMORY_SCOPE_AGENT);
}
__device__ __forceinline__ unsigned llc_flag(const unsigned* p) {
  return __hip_atomic_load(p, __ATOMIC_RELAXED, __HIP_MEMORY_SCOPE_AGENT);
}

// ---------------- init: zero flags, y0 into slot1 and ybuf ----------------
__global__ void k_init(float* __restrict__ slot1, float* __restrict__ ybuf,
                       const float* __restrict__ h0,
                       unsigned* __restrict__ flags) {
  int tid = blockIdx.x * 256 + threadIdx.x;
  if (tid < 512) flags[tid] = 0u;
  if (tid < BU) {
    float v = h0[tid & (U - 1)];
    slot1[tid] = v;
    ybuf[tid] = v;
  }
}

// ------- xproj[t*64+n][u] = emb[x[n][t]] @ w_x + b_in (R2/R3-proven) -------
__global__ __launch_bounds__(256) void k_xproj(
    const int* __restrict__ x, const float* __restrict__ emb,
    const float* __restrict__ w_x, const float* __restrict__ b_in,
    float* __restrict__ xp) {
  __shared__ float a_s[64][36];
  __shared__ float w_s[32][64];
  __shared__ int idxs[64];
  const int tid = threadIdx.x;
  const int m0 = blockIdx.x * 64;
  const int c0 = blockIdx.y * 64;
  if (tid < 64) {
    int m = m0 + tid;
    idxs[tid] = x[(m & 63) * T + (m >> 6)];  // x[n][t], row m = t*64+n
  }
  __syncthreads();
  const int rq = tid >> 4, cq = tid & 15;
  float acc[4][4] = {};
  for (int k0 = 0; k0 < E; k0 += 32) {
#pragma unroll
    for (int rep = 0; rep < 8; ++rep) {
      int e = rep * 256 + tid;
      int r = e >> 5, k = e & 31;
      a_s[r][k] = emb[(size_t)idxs[r] * E + k0 + k];
    }
#pragma unroll
    for (int rep = 0; rep < 2; ++rep) {
      int e = rep * 256 + tid;
      int kr = e >> 4, q = e & 15;
      *(float4*)&w_s[kr][4 * q] =
          *(const float4*)(w_x + (size_t)(k0 + kr) * U + c0 + 4 * q);
    }
    __syncthreads();
#pragma unroll
    for (int kc = 0; kc < 32; kc += 4) {
      float4 a4[4], w4[4];
#pragma unroll
      for (int i = 0; i < 4; ++i) a4[i] = *(const float4*)&a_s[4 * rq + i][kc];
#pragma unroll
      for (int kk = 0; kk < 4; ++kk)
        w4[kk] = *(const float4*)&w_s[kc + kk][4 * cq];
#pragma unroll
      for (int i = 0; i < 4; ++i) {
        const float av[4] = {a4[i].x, a4[i].y, a4[i].z, a4[i].w};
#pragma unroll
        for (int kk = 0; kk < 4; ++kk) {
          acc[i][0] += av[kk] * w4[kk].x;
          acc[i][1] += av[kk] * w4[kk].y;
          acc[i][2] += av[kk] * w4[kk].z;
          acc[i][3] += av[kk] * w4[kk].w;
        }
      }
    }
    __syncthreads();
  }
  const float4 bb = *(const float4*)(b_in + c0 + 4 * cq);
  const float bv[4] = {bb.x, bb.y, bb.z, bb.w};
#pragma unroll
  for (int i = 0; i < 4; ++i) {
    float4 o;
    o.x = acc[i][0] + bv[0];
    o.y = acc[i][1] + bv[1];
    o.z = acc[i][2] + bv[2];
    o.w = acc[i][3] + bv[3];
    *(float4*)(xp + (size_t)(m0 + 4 * rq + i) * U + c0 + 4 * cq) = o;
  }
}

// ---------------- sequential pipeline ----------------
// 256 WGs = 8 rg x 32 cg (XCD = cg&7, L2-affine). Thread (s,ri,ci): K-slice
// [32s,32s+32), rows [4ri,4ri+4) of 8, cols [4ci,4ci+4) of 32. Partials ->
// red2[s][out] pitch 264. a_s (8 x 1156 = 9248 floats) ALIASES red2 (32 x
// 264 = 8448) — barriers order A-read < red-write < red-read < next A-write.
__global__ __launch_bounds__(512, 2) void k_seq(
    const float* __restrict__ xp, const float* __restrict__ w_y,
    const float* __restrict__ w_h, const float* __restrict__ b_h,
    const float* __restrict__ w_out, const float* __restrict__ b_out,
    float* __restrict__ out, float* __restrict__ slots,
    float* __restrict__ ybuf, unsigned* __restrict__ flags) {
  __shared__ float smem[8 * APITCH];  // 9248 floats = 36992 B
  float* const a_s = smem;   // [row][36*(k>>5) + (k&31)] (injective skew)
  float* const red2 = smem;  // [s][out], pitch 264 (alias — see barriers)
  const int tid = threadIdx.x;
  const int cg = blockIdx.x & 31, rg = blockIdx.x >> 5;
  const int l = tid & 63;
  const int ci = l & 7, ri = (l >> 3) & 1;
  const int s = (tid >> 6) * 4 + ((l >> 4) & 3);
  const int cb = 4 * ci, r0 = 4 * ri, k0 = 32 * s;

  // W base selector for phase P
  auto wbase = [&](int P) -> const float* {
    const int p = P & 3;
    const float* Wsrc = (p == 0)   ? w_y
                        : (p == 3) ? w_out
                                   : w_h + (size_t)(p - 1) * U * U;
    return Wsrc + (size_t)k0 * U + 32 * cg + cb;
  };
  // ---- W prefetch for P=0 (static addresses -> latency off critical path) --
  f4 wreg[32];  // W[k0+j][cb..cb+4), j=0..31 -> 128 VGPRs
  {
    const float* wp = wbase(0);
#pragma unroll
    for (int j = 0; j < 32; ++j) wreg[j] = *(const f4*)(wp + (size_t)j * U);
  }

  for (int P = 0; P < 4 * T; ++P) {
    const int t = P >> 2, p = P & 3;
    const float* Asrc =
        slots + (size_t)((P + 1) & 1) * BU + (size_t)(8 * rg) * U;
    float* slotw = slots + (size_t)(P & 1) * BU;
    // ---- 1. poll flag[rg] (tid0, s_sleep backoff) ----
    if (P > 0) {
      if (tid == 0) {
        const unsigned tg = 32u * (unsigned)P;
        while (llc_flag(&flags[rg * 32]) < tg) __builtin_amdgcn_s_sleep(1);
      }
      __syncthreads();
      asm volatile("" ::: "memory");
    }
    // ---- 2. stage A: 8 rows x 1024, 8B sc1 loads -> single b128 LDS write --
#pragma unroll
    for (int rep = 0; rep < 4; ++rep) {
      int idx4 = 512 * rep + tid;  // f4 index in [0,2048)
      int row = idx4 >> 8, kq = idx4 & 255, k = 4 * kq;
      const float* pa = Asrc + (size_t)row * U + k;
      unsigned long long v0 = llc_load64(pa);
      unsigned long long v1 = llc_load64(pa + 2);
      f4 v;
      ((unsigned long long*)&v)[0] = v0;
      ((unsigned long long*)&v)[1] = v1;
      *(f4*)&a_s[row * APITCH + 36 * (k >> 5) + (k & 31)] = v;
    }
    __syncthreads();
    // ---- 3. main: 4x4x(K=32) tile; A from LDS, W from registers ----
    f4 acc[4];
#pragma unroll
    for (int i = 0; i < 4; ++i) acc[i] = (f4){0.f, 0.f, 0.f, 0.f};
    {
      const int abase = r0 * APITCH + 36 * s;  // 36*(k0>>5) = 36s
#pragma unroll
      for (int q = 0; q < 8; ++q) {
        const int ai = abase + 4 * q;
        f4 a0 = *(const f4*)&a_s[ai];
        f4 a1 = *(const f4*)&a_s[ai + APITCH];
        f4 a2 = *(const f4*)&a_s[ai + 2 * APITCH];
        f4 a3 = *(const f4*)&a_s[ai + 3 * APITCH];
        const f4 w0 = wreg[4 * q], w1 = wreg[4 * q + 1];
        const f4 w2 = wreg[4 * q + 2], w3 = wreg[4 * q + 3];
        acc[0] += a0.x * w0 + a0.y * w1 + a0.z * w2 + a0.w * w3;
        acc[1] += a1.x * w0 + a1.y * w1 + a1.z * w2 + a1.w * w3;
        acc[2] += a2.x * w0 + a2.y * w1 + a2.z * w2 + a2.w * w3;
        acc[3] += a3.x * w0 + a3.y * w1 + a3.z * w2 + a3.w * w3;
      }
    }
    __syncthreads();  // all a_s reads done -> safe to alias-write red2
    // ---- 4. write partials red2[s*264 + out], b128 ----
#pragma unroll
    for (int i = 0; i < 4; ++i)
      *(f4*)&red2[s * 264 + (r0 + i) * 32 + cb] = acc[i];
    __syncthreads();
    // ---- 5. finalize: 256 threads, sum 32 partials, bias+act, store ----
    if (tid < 256) {
      float sum = 0.f;
#pragma unroll
      for (int z = 0; z < 32; ++z) sum += red2[z * 264 + tid];
      const int row = 8 * rg + (tid >> 5);
      const int u = 32 * cg + (tid & 31);
      if (p == 0) {
        float v = sum + xp[((size_t)t * B + row) * U + u];
        llc_store(slotw + (size_t)row * U + u, LRELU(v));
      } else if (p < 3) {
        float v = sum + b_h[(p - 1) * U + u];
        llc_store(slotw + (size_t)row * U + u, LRELU(v));
      } else {
        const size_t yi = (size_t)row * U + u;
        float yn = ybuf[yi] + sum + b_out[u];  // WG-private: plain ok
        ybuf[yi] = yn;
        out[((size_t)row * T + t) * U + u] = yn;
        llc_store(slotw + yi, yn);  // y is next p0's A
      }
    }
    // ---- 6. drain ----
    asm volatile("" ::: "memory");
    __builtin_amdgcn_s_waitcnt(0);
    __syncthreads();
    // ---- 7. W prefetch for P+1 (issued BEFORE the flag post so the L2/HBM
    //         W traffic overlaps post + poll + A-stage of the next phase) ----
    if (P < 4 * T - 1) {
      const float* wp = wbase(P + 1);
#pragma unroll
      for (int j = 0; j < 32; ++j) wreg[j] = *(const f4*)(wp + (size_t)j * U);
    }
    if (tid == 0)
      __hip_atomic_fetch_add(&flags[rg * 32], 1u, __ATOMIC_RELAXED,
                             __HIP_MEMORY_SCOPE_AGENT);
  }
}

extern "C" void kernel_launch(void* const* d_in, const int* in_sizes, int n_in,
                              void* d_out, int out_size, void* d_ws,
                              size_t ws_size, hipStream_t stream) {
  const int* x = (const int*)d_in[0];
  const float* emb = (const float*)d_in[1];
  const float* w_y = (const float*)d_in[2];
  const float* w_x = (const float*)d_in[3];
  const float* b_in = (const float*)d_in[4];
  const float* w_h = (const float*)d_in[5];
  const float* b_h = (const float*)d_in[6];
  const float* w_out = (const float*)d_in[7];
  const float* b_out = (const float*)d_in[8];
  const float* h0 = (const float*)d_in[9];
  float* out = (float*)d_out;

  // workspace (floats): xproj | slots[2] | ybuf | flags
  float* ws = (float*)d_ws;
  float* xpb = ws;                         // T*B*U
  float* slots = xpb + (size_t)T * B * U;  // 2*BU
  float* ybuf = slots + 2 * (size_t)BU;    // BU
  unsigned* flags = (unsigned*)(ybuf + (size_t)BU);  // 512 uints

  k_init<<<256, 256, 0, stream>>>(slots + (size_t)BU, ybuf, h0, flags);
  dim3 g1(256, 16);
  k_xproj<<<g1, 256, 0, stream>>>(x, emb, w_x, b_in, xpb);

  void* args[] = {&xpb,   &w_y, &w_h,   &b_h,  &w_out,
                  &b_out, &out, &slots, &ybuf, &flags};
  hipLaunchCooperativeKernel((void*)k_seq, dim3(256), dim3(512), args, 0u,
                             stream);
}